// Round 4
// baseline (317.232 us; speedup 1.0000x reference)
//
#include <hip/hip_runtime.h>
#include <math.h>

#define NN  100000
#define NNP 100352            // NN padded to a multiple of 1024
#define NE  1200000
#define D   64
#define BN_EPS 1e-5f
#define NBLK (NNP / 1024)     // 98 scan blocks

__device__ __forceinline__ float bcastf(float v, int srcLane) {
    return __int_as_float(__builtin_amdgcn_readlane(__float_as_int(v), srcLane));
}
__device__ __forceinline__ unsigned bf16rne(float f) {
    unsigned u = __float_as_uint(f);
    return (u + 0x7FFFu + ((u >> 16) & 1u)) >> 16;
}
__device__ __forceinline__ void acc_bf16(float4& acc, uint2 a) {
    acc.x += __uint_as_float(a.x << 16);
    acc.y += __uint_as_float(a.x & 0xffff0000u);
    acc.z += __uint_as_float(a.y << 16);
    acc.w += __uint_as_float(a.y & 0xffff0000u);
}

// ---------------------------------------------------------------------------
// x (f32) -> xb (bf16, RNE). Row = 64 bf16 = 128B = 16 uint2.
// ---------------------------------------------------------------------------
__global__ __launch_bounds__(256) void cvt_kernel(
        const float4* __restrict__ xv, uint2* __restrict__ xb) {
    int gid = blockIdx.x * 256 + threadIdx.x;        // over NN*16 = 1.6M exact
    float4 v = xv[gid];
    uint2 o;
    o.x = bf16rne(v.x) | (bf16rne(v.y) << 16);
    o.y = bf16rne(v.z) | (bf16rne(v.w) << 16);
    xb[gid] = o;
}

// ---------------------------------------------------------------------------
// CSR step 1: histogram of dst, int4-vectorized (4 edges/thread).
// ---------------------------------------------------------------------------
__global__ __launch_bounds__(256) void hist_kernel(
        const int4* __restrict__ dstv, int* __restrict__ count) {
    int i = blockIdx.x * 256 + threadIdx.x;          // over NE/4 = 300000
    if (i >= NE / 4) return;
    int4 d = dstv[i];
    atomicAdd(&count[d.x], 1);
    atomicAdd(&count[d.y], 1);
    atomicAdd(&count[d.z], 1);
    atomicAdd(&count[d.w], 1);
}

// ---------------------------------------------------------------------------
// CSR step 2a: per-block exclusive scan (1024 ints/block) via int4 + shfl.
// ---------------------------------------------------------------------------
__global__ __launch_bounds__(256) void scan1_kernel(
        const int4* __restrict__ countv, int4* __restrict__ excv,
        int* __restrict__ bsum) {
    __shared__ int wsum[4];
    __shared__ int wexc[4];
    const int tid  = threadIdx.x;
    const int lane = tid & 63;
    const int wid  = tid >> 6;
    const int idx  = blockIdx.x * 256 + tid;

    int4 v = countv[idx];                    // padded region is zeroed
    const int s = v.x + v.y + v.z + v.w;
    int incl = s;
    #pragma unroll
    for (int off = 1; off < 64; off <<= 1) {
        int n = __shfl_up(incl, off, 64);
        if (lane >= off) incl += n;
    }
    if (lane == 63) wsum[wid] = incl;
    __syncthreads();
    if (tid == 0) {
        int r = 0;
        #pragma unroll
        for (int w = 0; w < 4; ++w) { wexc[w] = r; r += wsum[w]; }
        bsum[blockIdx.x] = r;
    }
    __syncthreads();
    const int base = wexc[wid] + (incl - s);
    int4 e;
    e.x = base;
    e.y = e.x + v.x;
    e.z = e.y + v.y;
    e.w = e.z + v.z;
    excv[idx] = e;
}

// ---------------------------------------------------------------------------
// CSR step 2b+2c merged: every block scans the 98 block sums in LDS, then
// combines -> start[]; init cursor[].
// ---------------------------------------------------------------------------
__global__ __launch_bounds__(256) void scan23_kernel(
        const int* __restrict__ bsum, const int* __restrict__ exc,
        int* __restrict__ start, int* __restrict__ cursor) {
    __shared__ int pre[NBLK];
    for (int b = threadIdx.x; b < NBLK; b += 256) pre[b] = bsum[b];
    __syncthreads();
    if (threadIdx.x == 0) {                   // 98 adds from LDS, pipelined
        int r = 0;
        #pragma unroll 2
        for (int b = 0; b < NBLK; ++b) { int t = pre[b]; pre[b] = r; r += t; }
    }
    __syncthreads();
    int i = blockIdx.x * 256 + threadIdx.x;
    if (i < NN) {
        int s = exc[i] + pre[i >> 10];
        start[i] = s;
        cursor[i] = s;
    }
    if (i == 0) start[NN] = NE;
}

// ---------------------------------------------------------------------------
// CSR step 3: bucket src by dst, int4-vectorized (4 edges/thread).
// ---------------------------------------------------------------------------
__global__ __launch_bounds__(256) void reorder_kernel(
        const int4* __restrict__ srcv, const int4* __restrict__ dstv,
        int* __restrict__ cursor, int* __restrict__ srcSorted) {
    int i = blockIdx.x * 256 + threadIdx.x;          // over NE/4
    if (i >= NE / 4) return;
    int4 s = srcv[i];
    int4 d = dstv[i];
    srcSorted[atomicAdd(&cursor[d.x], 1)] = s.x;
    srcSorted[atomicAdd(&cursor[d.y], 1)] = s.y;
    srcSorted[atomicAdd(&cursor[d.z], 1)] = s.z;
    srcSorted[atomicAdd(&cursor[d.w], 1)] = s.w;
}

// ---------------------------------------------------------------------------
// Fused gather(bf16) -> mean -> @W -> ELU -> h + BN-stat partials.
// Quarter-wave (16 lanes) per node; lane t owns features 4t..4t+3.
// 4 edges (4 idx + 4 row loads) in flight per lane. GEMM broadcasts the
// quarter-wave accumulator via v_readlane (compile-time lane ids).
// NN % 16 == 0 -> no bounds checks in the main loop.
// ---------------------------------------------------------------------------
__global__ __launch_bounds__(256) void agg_gemm_kernel(
        const uint2* __restrict__ xb,           // [NN][16] uint2 (bf16 rows)
        const int*   __restrict__ start,
        const int*   __restrict__ srcSorted,
        const float* __restrict__ W,            // [D_IN, D_OUT] row-major
        float* __restrict__ h,
        float* __restrict__ stats) {            // [0..63]=sum, [64..127]=sumsq
    __shared__ float4 Wt2[16 * 64];             // [k0][c] = W[4k0..4k0+3][c]
    __shared__ float red[2][256];

    for (int i = threadIdx.x; i < D * D; i += 256) {
        const float val = W[i];
        const int k = i >> 6, c = i & 63;
        ((float*)&Wt2[(k >> 2) * 64 + c])[k & 3] = val;
    }
    __syncthreads();

    const int w    = threadIdx.x >> 6;          // wave slot 0..3
    const int lane = threadIdx.x & 63;
    const int q    = lane >> 4;                 // quarter-wave = node slot
    const int t    = lane & 15;                 // uint2 slot within row

    float s = 0.f, s2 = 0.f;
    const int nIter = NN / 16;                  // 6250, exact
    for (int it = blockIdx.x; it < nIter; it += gridDim.x) {
        const int node = it * 16 + w * 4 + q;
        const int e0 = start[node], e1 = start[node + 1];
        float4 acc = make_float4(0.f, 0.f, 0.f, 0.f);
        int j = e0;
        for (; j + 4 <= e1; j += 4) {           // 4 rows in flight per lane
            const int s0 = srcSorted[j];
            const int s1 = srcSorted[j + 1];
            const int s2i = srcSorted[j + 2];
            const int s3 = srcSorted[j + 3];
            const uint2 a0 = xb[(size_t)s0 * 16 + t];
            const uint2 a1 = xb[(size_t)s1 * 16 + t];
            const uint2 a2 = xb[(size_t)s2i * 16 + t];
            const uint2 a3 = xb[(size_t)s3 * 16 + t];
            acc_bf16(acc, a0);
            acc_bf16(acc, a1);
            acc_bf16(acc, a2);
            acc_bf16(acc, a3);
        }
        for (; j < e1; ++j) {
            const int s0 = srcSorted[j];
            acc_bf16(acc, xb[(size_t)s0 * 16 + t]);
        }
        const float deg = (float)(e1 - e0);

        // GEMM: 4 nodes per wave, broadcast via readlane (uniform lane ids)
        #pragma unroll
        for (int qq = 0; qq < 4; ++qq) {
            float hacc = 0.f;
            #pragma unroll
            for (int k0 = 0; k0 < 16; ++k0) {
                const float4 wv = Wt2[k0 * 64 + lane];
                const int src = qq * 16 + k0;
                hacc = fmaf(bcastf(acc.x, src), wv.x, hacc);
                hacc = fmaf(bcastf(acc.y, src), wv.y, hacc);
                hacc = fmaf(bcastf(acc.z, src), wv.z, hacc);
                hacc = fmaf(bcastf(acc.w, src), wv.w, hacc);
            }
            const float invq = 1.0f / fmaxf(bcastf(deg, qq * 16), 1.0f);
            hacc *= invq;                       // (agg*inv)@W == inv*(agg@W)
            const float hv = hacc > 0.f ? hacc : expm1f(hacc);
            const int nodeq = it * 16 + w * 4 + qq;
            h[(size_t)nodeq * 64 + lane] = hv;
            s  += hv;
            s2 += hv * hv;
        }
    }

    red[0][threadIdx.x] = s;
    red[1][threadIdx.x] = s2;
    __syncthreads();
    if (threadIdx.x < 64) {
        float ts  = red[0][threadIdx.x] + red[0][threadIdx.x + 64] +
                    red[0][threadIdx.x + 128] + red[0][threadIdx.x + 192];
        float ts2 = red[1][threadIdx.x] + red[1][threadIdx.x + 64] +
                    red[1][threadIdx.x + 128] + red[1][threadIdx.x + 192];
        atomicAdd(&stats[threadIdx.x],      ts);
        atomicAdd(&stats[64 + threadIdx.x], ts2);
    }
}

// ---------------------------------------------------------------------------
// BatchNorm finalize, float4-vectorized streaming.
// ---------------------------------------------------------------------------
__global__ __launch_bounds__(256) void bn_kernel(
        const float4* __restrict__ h,
        const float*  __restrict__ stats,
        const float*  __restrict__ gamma,
        const float*  __restrict__ beta,
        float4* __restrict__ out) {
    int gid = blockIdx.x * 256 + threadIdx.x;     // over NN*D/4 = 1.6M exact
    const int c0 = (gid & 15) * 4;
    const float4 v = h[gid];
    float4 r;
    const float* vv = (const float*)&v;
    float* rr = (float*)&r;
    #pragma unroll
    for (int k = 0; k < 4; ++k) {
        const int c = c0 + k;
        const float mu  = stats[c] * (1.0f / NN);
        const float var = stats[64 + c] * (1.0f / NN) - mu * mu;
        const float is  = rsqrtf(var + BN_EPS);
        rr[k] = (vv[k] - mu) * is * gamma[c] + beta[c];
    }
    out[gid] = r;
}

extern "C" void kernel_launch(void* const* d_in, const int* in_sizes, int n_in,
                              void* d_out, int out_size, void* d_ws, size_t ws_size,
                              hipStream_t stream) {
    const float* x     = (const float*)d_in[0];
    const int*   ei    = (const int*)  d_in[1];
    const float* W     = (const float*)d_in[2];
    const float* gamma = (const float*)d_in[3];
    const float* beta  = (const float*)d_in[4];
    float* out = (float*)d_out;

    // workspace layout (4B units):
    // [buf NN*D][count NNP][stats 128][exc NNP][start NN+1(+pad)][cursor NN]
    // [bsum 128][srcSorted NE][xb NN*32 (bf16 rows, 8B granules)]
    float* buf       = (float*)d_ws;
    int*   count     = (int*)(buf + (size_t)NN * D);
    float* stats     = (float*)(count + NNP);
    int*   exc       = (int*)(stats + 128);
    int*   start     = exc + NNP;
    int*   cursor    = start + NN + 4;
    int*   bsum      = cursor + NN;
    int*   srcSorted = bsum + 128;
    uint2* xb        = (uint2*)(srcSorted + NE);

    // zero count (incl. padding) + stats — contiguous
    hipMemsetAsync(count, 0, (size_t)(NNP + 128) * sizeof(int), stream);

    cvt_kernel    <<<NN * 16 / 256, 256, 0, stream>>>((const float4*)x, xb);
    hist_kernel   <<<(NE / 4 + 255) / 256, 256, 0, stream>>>(
        (const int4*)(ei + NE), count);
    scan1_kernel  <<<NBLK, 256, 0, stream>>>((const int4*)count, (int4*)exc, bsum);
    scan23_kernel <<<(NN + 255) / 256, 256, 0, stream>>>(bsum, exc, start, cursor);
    reorder_kernel<<<(NE / 4 + 255) / 256, 256, 0, stream>>>(
        (const int4*)ei, (const int4*)(ei + NE), cursor, srcSorted);
    agg_gemm_kernel<<<2048, 256, 0, stream>>>(xb, start, srcSorted, W, buf, stats);
    bn_kernel     <<<NN * D / 4 / 256, 256, 0, stream>>>(
        (const float4*)buf, stats, gamma, beta, (float4*)out);
}

// Round 5
// 289.147 us; speedup vs baseline: 1.0971x; 1.0971x over previous
//
#include <hip/hip_runtime.h>
#include <math.h>

#define NN     100000
#define NE     1200000
#define D      64
#define BN_EPS 1e-5f
#define CHUNK  8192
#define NCHUNK ((NE + CHUNK - 1) / CHUNK)    // 147
#define NB     ((NN + 511) / 512)            // 196 buckets of 512 nodes
#define CSIZE  (NB * NCHUNK)                 // 28812
#define SL     ((CSIZE + 255) / 256)         // 113 scan elems per thread
#define CAPD   8192                          // max edges per bucket (safety)

__device__ __forceinline__ float bcastf(float v, int srcLane) {
    return __int_as_float(__builtin_amdgcn_readlane(__float_as_int(v), srcLane));
}
__device__ __forceinline__ unsigned bf16rne(float f) {
    unsigned u = __float_as_uint(f);
    return (u + 0x7FFFu + ((u >> 16) & 1u)) >> 16;
}
__device__ __forceinline__ void acc_bf16(float4& acc, uint2 a) {
    acc.x += __uint_as_float(a.x << 16);
    acc.y += __uint_as_float(a.x & 0xffff0000u);
    acc.z += __uint_as_float(a.y << 16);
    acc.w += __uint_as_float(a.y & 0xffff0000u);
}
// exclusive prefix of s across the 256 threads of the block
__device__ __forceinline__ int block_scan_excl(int s, int* wsum, int* wexc) {
    const int lane = threadIdx.x & 63, wid = threadIdx.x >> 6;
    int incl = s;
    #pragma unroll
    for (int off = 1; off < 64; off <<= 1) {
        int n = __shfl_up(incl, off, 64);
        if (lane >= off) incl += n;
    }
    if (lane == 63) wsum[wid] = incl;
    __syncthreads();
    if (threadIdx.x == 0) {
        int r = 0;
        #pragma unroll
        for (int w = 0; w < 4; ++w) { wexc[w] = r; r += wsum[w]; }
    }
    __syncthreads();
    return wexc[wid] + incl - s;
}

// ---------------------------------------------------------------------------
// x (f32) -> xb (bf16, RNE). Row = 64 bf16 = 128B = 16 uint2.
// ---------------------------------------------------------------------------
__global__ __launch_bounds__(256) void cvt_kernel(
        const float4* __restrict__ xv, uint2* __restrict__ xb) {
    int gid = blockIdx.x * 256 + threadIdx.x;        // over NN*16 = 1.6M exact
    float4 v = xv[gid];
    uint2 o;
    o.x = bf16rne(v.x) | (bf16rne(v.y) << 16);
    o.y = bf16rne(v.z) | (bf16rne(v.w) << 16);
    xb[gid] = o;
}

// ---------------------------------------------------------------------------
// Build pass A: per-chunk LDS histogram over NB coarse buckets.
// ---------------------------------------------------------------------------
__global__ __launch_bounds__(256) void chunk_hist_kernel(
        const int* __restrict__ dst, int* __restrict__ c) {
    __shared__ int hist[256];
    const int tid = threadIdx.x;
    const int i = blockIdx.x;
    const int e0 = i * CHUNK;
    const int n = min(CHUNK, NE - e0);
    hist[tid] = 0;
    __syncthreads();
    for (int k = tid; k < n; k += 256)
        atomicAdd(&hist[dst[e0 + k] >> 9], 1);
    __syncthreads();
    if (tid < NB) c[tid * NCHUNK + i] = hist[tid];
}

// ---------------------------------------------------------------------------
// Build pass B: exclusive scan of c (bucket-major, 28812 entries), in place.
// c[b*NCHUNK+i] becomes the global offset of chunk i's run in bucket b;
// c[b*NCHUNK] is bucket b's start.
// ---------------------------------------------------------------------------
__global__ __launch_bounds__(256) void scan_c_kernel(int* __restrict__ c) {
    __shared__ int wsum[4], wexc[4];
    const int base = threadIdx.x * SL;
    int s = 0;
    for (int k = 0; k < SL; ++k) {
        const int idx = base + k;
        if (idx < CSIZE) s += c[idx];
    }
    const int ex = block_scan_excl(s, wsum, wexc);
    int r = ex;
    for (int k = 0; k < SL; ++k) {
        const int idx = base + k;
        if (idx < CSIZE) { const int t = c[idx]; c[idx] = r; r += t; }
    }
}

// ---------------------------------------------------------------------------
// Build pass C: each block locally sorts its 8192-edge chunk by bucket in
// LDS, then writes bucket-contiguous runs to `binned` (coalesced runs,
// ~170B avg). Record = (src<<9) | (dst & 511), 26 bits.
// ---------------------------------------------------------------------------
__global__ __launch_bounds__(256) void chunk_scatter_kernel(
        const int* __restrict__ src, const int* __restrict__ dst,
        const int* __restrict__ cbase, int* __restrict__ binned) {
    __shared__ int hist[256];            // becomes local bucket start
    __shared__ int lcur[256];
    __shared__ int cbaseL[256];
    __shared__ int sorted[CHUNK];        // 32 KB
    __shared__ unsigned char bOf[CHUNK]; // 8 KB
    __shared__ int wsum[4], wexc[4];
    const int tid = threadIdx.x;
    const int i = blockIdx.x;
    const int e0 = i * CHUNK;
    const int n = min(CHUNK, NE - e0);

    hist[tid] = 0;
    if (tid < NB) cbaseL[tid] = cbase[tid * NCHUNK + i];
    __syncthreads();
    for (int k = tid; k < n; k += 256)
        atomicAdd(&hist[dst[e0 + k] >> 9], 1);
    __syncthreads();
    const int h = hist[tid];                       // own slot only
    const int ex = block_scan_excl(h, wsum, wexc);
    hist[tid] = ex;                                // own slot only
    lcur[tid] = ex;
    __syncthreads();
    for (int k = tid; k < n; k += 256) {
        const int dv = dst[e0 + k];
        const int b = dv >> 9;
        const int slot = atomicAdd(&lcur[b], 1);
        sorted[slot] = (src[e0 + k] << 9) | (dv & 511);
        bOf[slot] = (unsigned char)b;
    }
    __syncthreads();
    for (int k = tid; k < n; k += 256) {
        const int b = bOf[k];
        binned[cbaseL[b] + (k - hist[b])] = sorted[k];
    }
}

// ---------------------------------------------------------------------------
// Build pass D: per-bucket counting sort fully in LDS -> start[] (global
// CSR) + srcSorted. All global reads/writes coalesced; LDS atomics only.
// ---------------------------------------------------------------------------
__global__ __launch_bounds__(256) void bucket_csr_kernel(
        const int* __restrict__ binned, const int* __restrict__ cbase,
        int* __restrict__ start, int* __restrict__ srcSorted) {
    __shared__ int lhist[512];
    __shared__ int lcur[512];
    __shared__ int sortedS[CAPD];        // 32 KB
    __shared__ int wsum[4], wexc[4];
    const int tid = threadIdx.x;
    const int b = blockIdx.x;
    const int n0 = b * 512;
    const int nb = min(512, NN - n0);
    const int lo = cbase[b * NCHUNK];
    const int hi = (b == NB - 1) ? NE : cbase[(b + 1) * NCHUNK];
    int cnt = hi - lo;
    if (cnt > CAPD) cnt = CAPD;          // impossible for this input; no OOB

    lhist[tid] = 0; lhist[tid + 256] = 0;
    __syncthreads();
    for (int k = tid; k < cnt; k += 256)
        atomicAdd(&lhist[binned[lo + k] & 511], 1);
    __syncthreads();
    const int h0 = lhist[2 * tid], h1 = lhist[2 * tid + 1];  // own slots
    const int ex = block_scan_excl(h0 + h1, wsum, wexc);
    lhist[2 * tid] = ex;      lhist[2 * tid + 1] = ex + h0;
    lcur[2 * tid] = ex;       lcur[2 * tid + 1] = ex + h0;
    __syncthreads();
    for (int l = tid; l < nb; l += 256) start[n0 + l] = lo + lhist[l];
    if (b == NB - 1 && tid == 0) start[NN] = NE;
    for (int k = tid; k < cnt; k += 256) {
        const int rec = binned[lo + k];
        const int slot = atomicAdd(&lcur[rec & 511], 1);
        sortedS[slot] = rec >> 9;
    }
    __syncthreads();
    for (int k = tid; k < cnt; k += 256) srcSorted[lo + k] = sortedS[k];
}

// ---------------------------------------------------------------------------
// Fused gather(bf16) -> mean -> @W -> ELU -> h + BN-stat partials.
// Quarter-wave (16 lanes) per node; lane t owns features 4t..4t+3.
// ---------------------------------------------------------------------------
__global__ __launch_bounds__(256) void agg_gemm_kernel(
        const uint2* __restrict__ xb,           // [NN][16] uint2 (bf16 rows)
        const int*   __restrict__ start,
        const int*   __restrict__ srcSorted,
        const float* __restrict__ W,            // [D_IN, D_OUT] row-major
        float* __restrict__ h,
        float* __restrict__ stats) {            // [0..63]=sum, [64..127]=sumsq
    __shared__ float4 Wt2[16 * 64];             // [k0][c] = W[4k0..4k0+3][c]
    __shared__ float red[2][256];

    for (int i = threadIdx.x; i < D * D; i += 256) {
        const float val = W[i];
        const int k = i >> 6, c = i & 63;
        ((float*)&Wt2[(k >> 2) * 64 + c])[k & 3] = val;
    }
    __syncthreads();

    const int w    = threadIdx.x >> 6;          // wave slot 0..3
    const int lane = threadIdx.x & 63;
    const int q    = lane >> 4;                 // quarter-wave = node slot
    const int t    = lane & 15;                 // uint2 slot within row

    float s = 0.f, s2 = 0.f;
    const int nIter = NN / 16;                  // 6250, exact
    for (int it = blockIdx.x; it < nIter; it += gridDim.x) {
        const int node = it * 16 + w * 4 + q;
        const int e0 = start[node], e1 = start[node + 1];
        float4 acc = make_float4(0.f, 0.f, 0.f, 0.f);
        int j = e0;
        for (; j + 4 <= e1; j += 4) {           // 4 rows in flight per lane
            const int s0 = srcSorted[j];
            const int s1 = srcSorted[j + 1];
            const int s2i = srcSorted[j + 2];
            const int s3 = srcSorted[j + 3];
            const uint2 a0 = xb[(size_t)s0 * 16 + t];
            const uint2 a1 = xb[(size_t)s1 * 16 + t];
            const uint2 a2 = xb[(size_t)s2i * 16 + t];
            const uint2 a3 = xb[(size_t)s3 * 16 + t];
            acc_bf16(acc, a0);
            acc_bf16(acc, a1);
            acc_bf16(acc, a2);
            acc_bf16(acc, a3);
        }
        for (; j < e1; ++j) {
            const int s0 = srcSorted[j];
            acc_bf16(acc, xb[(size_t)s0 * 16 + t]);
        }
        const float deg = (float)(e1 - e0);

        // GEMM: 4 nodes per wave, broadcast via readlane (uniform lane ids)
        #pragma unroll
        for (int qq = 0; qq < 4; ++qq) {
            float hacc = 0.f;
            #pragma unroll
            for (int k0 = 0; k0 < 16; ++k0) {
                const float4 wv = Wt2[k0 * 64 + lane];
                const int srcL = qq * 16 + k0;
                hacc = fmaf(bcastf(acc.x, srcL), wv.x, hacc);
                hacc = fmaf(bcastf(acc.y, srcL), wv.y, hacc);
                hacc = fmaf(bcastf(acc.z, srcL), wv.z, hacc);
                hacc = fmaf(bcastf(acc.w, srcL), wv.w, hacc);
            }
            const float invq = 1.0f / fmaxf(bcastf(deg, qq * 16), 1.0f);
            hacc *= invq;                       // (agg*inv)@W == inv*(agg@W)
            const float hv = hacc > 0.f ? hacc : expm1f(hacc);
            const int nodeq = it * 16 + w * 4 + qq;
            h[(size_t)nodeq * 64 + lane] = hv;
            s  += hv;
            s2 += hv * hv;
        }
    }

    red[0][threadIdx.x] = s;
    red[1][threadIdx.x] = s2;
    __syncthreads();
    if (threadIdx.x < 64) {
        float ts  = red[0][threadIdx.x] + red[0][threadIdx.x + 64] +
                    red[0][threadIdx.x + 128] + red[0][threadIdx.x + 192];
        float ts2 = red[1][threadIdx.x] + red[1][threadIdx.x + 64] +
                    red[1][threadIdx.x + 128] + red[1][threadIdx.x + 192];
        atomicAdd(&stats[threadIdx.x],      ts);
        atomicAdd(&stats[64 + threadIdx.x], ts2);
    }
}

// ---------------------------------------------------------------------------
// BatchNorm finalize, float4-vectorized streaming.
// ---------------------------------------------------------------------------
__global__ __launch_bounds__(256) void bn_kernel(
        const float4* __restrict__ h,
        const float*  __restrict__ stats,
        const float*  __restrict__ gamma,
        const float*  __restrict__ beta,
        float4* __restrict__ out) {
    int gid = blockIdx.x * 256 + threadIdx.x;     // over NN*D/4 = 1.6M exact
    const int c0 = (gid & 15) * 4;
    const float4 v = h[gid];
    float4 r;
    const float* vv = (const float*)&v;
    float* rr = (float*)&r;
    #pragma unroll
    for (int k = 0; k < 4; ++k) {
        const int c = c0 + k;
        const float mu  = stats[c] * (1.0f / NN);
        const float var = stats[64 + c] * (1.0f / NN) - mu * mu;
        const float is  = rsqrtf(var + BN_EPS);
        rr[k] = (vv[k] - mu) * is * gamma[c] + beta[c];
    }
    out[gid] = r;
}

extern "C" void kernel_launch(void* const* d_in, const int* in_sizes, int n_in,
                              void* d_out, int out_size, void* d_ws, size_t ws_size,
                              hipStream_t stream) {
    const float* x     = (const float*)d_in[0];
    const int*   ei    = (const int*)  d_in[1];
    const float* W     = (const float*)d_in[2];
    const float* gamma = (const float*)d_in[3];
    const float* beta  = (const float*)d_in[4];
    float* out = (float*)d_out;

    // workspace layout (4B units):
    // [buf NN*D  (binned NE ints overlays its head during CSR build)]
    // [stats 128][start NN+4][c CSIZE][srcSorted NE][xb NN*16 uint2]
    float* buf       = (float*)d_ws;
    int*   binned    = (int*)buf;                    // dead before agg_gemm
    float* stats     = buf + (size_t)NN * D;
    int*   start     = (int*)(stats + 128);
    int*   c         = start + NN + 4;
    int*   srcSorted = c + CSIZE;
    uint2* xb        = (uint2*)(srcSorted + NE);

    hipMemsetAsync(stats, 0, 128 * sizeof(float), stream);

    cvt_kernel        <<<NN * 16 / 256, 256, 0, stream>>>((const float4*)x, xb);
    chunk_hist_kernel <<<NCHUNK, 256, 0, stream>>>(ei + NE, c);
    scan_c_kernel     <<<1, 256, 0, stream>>>(c);
    chunk_scatter_kernel<<<NCHUNK, 256, 0, stream>>>(ei, ei + NE, c, binned);
    bucket_csr_kernel <<<NB, 256, 0, stream>>>(binned, c, start, srcSorted);
    agg_gemm_kernel   <<<2048, 256, 0, stream>>>(xb, start, srcSorted, W, buf, stats);
    bn_kernel         <<<NN * D / 4 / 256, 256, 0, stream>>>(
        (const float4*)buf, stats, gamma, beta, (float4*)out);
}